// Round 1
// baseline (130.271 us; speedup 1.0000x reference)
//
#include <hip/hip_runtime.h>
#include <hip/hip_bf16.h>

#define ROWS 1025   // B*N + 1
#define DD   128    // D
#define C3   384    // 3*D
#define BB   8
#define NN   128

__device__ __forceinline__ float fsigmoid(float x) {
    // 1/(1+exp(-x)); exp(-x)->inf handled: rcp(inf)=0
    return __builtin_amdgcn_rcpf(1.0f + __expf(-x));
}
__device__ __forceinline__ float ftanh(float x) {
    // 1 - 2/(exp(2x)+1); exp->inf => rcp->0 => 1; exp->0 => -1
    return 1.0f - 2.0f * __builtin_amdgcn_rcpf(__expf(2.0f * x) + 1.0f);
}

// Gi[r][c] = dot(h[r], Wi[c]) + bi[c]; Gh[r][c] = dot(h[r], Wh[c]) + bh[c]
// 4 hidden rows per block, 256 threads; thread t covers combined cols t, t+256, t+512 of 768.
__global__ __launch_bounds__(256) void gtab_kernel(
    const float* __restrict__ h,
    const float* __restrict__ Wi, const float* __restrict__ Wh,
    const float* __restrict__ bi, const float* __restrict__ bh,
    float* __restrict__ Gi, float* __restrict__ Gh) {
    __shared__ float hs[4][DD];
    const int t  = threadIdx.x;
    const int r0 = blockIdx.x * 4;
    for (int idx = t; idx < 4 * DD; idx += 256) {
        int r = idx >> 7, k = idx & (DD - 1);
        hs[r][k] = (r0 + r < ROWS) ? h[(r0 + r) * DD + k] : 0.0f;
    }
    __syncthreads();
#pragma unroll
    for (int jj = 0; jj < 3; ++jj) {
        const int  c   = t + jj * 256;     // 0..767
        const bool isI = (c < C3);
        const int  cc  = isI ? c : c - C3;
        const float* __restrict__ w = (isI ? Wi : Wh) + cc * DD;
        float acc[4] = {0.f, 0.f, 0.f, 0.f};
        for (int k = 0; k < DD; k += 4) {
            float4 wv = *reinterpret_cast<const float4*>(w + k);
#pragma unroll
            for (int r = 0; r < 4; ++r) {
                acc[r] += hs[r][k] * wv.x + hs[r][k + 1] * wv.y
                        + hs[r][k + 2] * wv.z + hs[r][k + 3] * wv.w;
            }
        }
        const float bv = (isI ? bi : bh)[cc];
        float* __restrict__ G = isI ? Gi : Gh;
#pragma unroll
        for (int r = 0; r < 4; ++r) {
            if (r0 + r < ROWS) G[(r0 + r) * C3 + cc] = acc[r] + bv;
        }
    }
}

// One block per (b, j); thread d accumulates change[b][j][d] over i.
// x_is_child=1: x=child, h=parent (bwd phase); 0: x=parent, h=child (fwd phase).
__global__ __launch_bounds__(128) void phase_kernel(
    const float* __restrict__ hin,
    const int* __restrict__ parent, const int* __restrict__ child,
    const float* __restrict__ Gi, const float* __restrict__ Gh,
    float* __restrict__ hout, int x_is_child) {
    const int bj = blockIdx.x;          // 0..1023
    const int b  = bj >> 7;
    const int j  = bj & (NN - 1);
    const int d  = threadIdx.x;         // 0..127

    __shared__ int xs[NN], hsx[NN];
    {
        const int i = d;
        const int p = parent[b * NN * NN + i * NN + j];
        const int c = child [b * NN * NN + i * NN + j];
        xs [i] = x_is_child ? c : p;
        hsx[i] = x_is_child ? p : c;
    }
    __syncthreads();

    float acc = 0.0f;
#pragma unroll 2
    for (int i = 0; i < NN; ++i) {
        const int xi = xs[i];
        const int hi = hsx[i];
        const float* __restrict__ gx = Gi + xi * C3;
        const float* __restrict__ gh = Gh + hi * C3;
        const float ir = gx[d], iz = gx[DD + d], in_ = gx[2 * DD + d];
        const float hr = gh[d], hz = gh[DD + d], hn  = gh[2 * DD + d];
        const float hv = hin[hi * DD + d];
        const float r = fsigmoid(ir + hr);
        const float z = fsigmoid(iz + hz);
        const float n = ftanh(in_ + r * hn);
        acc += (1.0f - z) * n + z * hv;
    }
    const int row = 1 + bj;
    hout[row * DD + d] = hin[row * DD + d] + acc;
    if (bj == 0) hout[d] = hin[d];      // row 0: change is zero
}

__global__ void out_kernel(const float* __restrict__ h, const int* __restrict__ tgt,
                           float* __restrict__ out) {
    const int b = blockIdx.x;
    const int d = threadIdx.x;
    out[b * DD + d] = h[tgt[b] * DD + d];
}

extern "C" void kernel_launch(void* const* d_in, const int* in_sizes, int n_in,
                              void* d_out, int out_size, void* d_ws, size_t ws_size,
                              hipStream_t stream) {
    const float* hidden = (const float*)d_in[0];
    const int*   parent = (const int*)d_in[1];
    const int*   child  = (const int*)d_in[2];
    const int*   tgt    = (const int*)d_in[3];
    const float* Wif    = (const float*)d_in[4];
    const float* Whf    = (const float*)d_in[5];
    const float* bif    = (const float*)d_in[6];
    const float* bhf    = (const float*)d_in[7];
    const float* Wib    = (const float*)d_in[8];
    const float* Whb    = (const float*)d_in[9];
    const float* bib    = (const float*)d_in[10];
    const float* bhb    = (const float*)d_in[11];

    float* ws = (float*)d_ws;
    float* Gi = ws;                       // ROWS*C3
    float* Gh = Gi + ROWS * C3;           // ROWS*C3
    float* h1 = Gh + ROWS * C3;           // ROWS*DD
    float* h2 = h1 + ROWS * DD;           // ROWS*DD
    float* out = (float*)d_out;

    const int gtab_grid = (ROWS + 3) / 4; // 257

    // Phase 1: bwd weights, x = child, h = parent
    gtab_kernel<<<gtab_grid, 256, 0, stream>>>(hidden, Wib, Whb, bib, bhb, Gi, Gh);
    phase_kernel<<<BB * NN, DD, 0, stream>>>(hidden, parent, child, Gi, Gh, h1, 1);
    // Phase 2: fwd weights, x = parent, h = child
    gtab_kernel<<<gtab_grid, 256, 0, stream>>>(h1, Wif, Whf, bif, bhf, Gi, Gh);
    phase_kernel<<<BB * NN, DD, 0, stream>>>(h1, parent, child, Gi, Gh, h2, 0);
    // Output gather
    out_kernel<<<BB, DD, 0, stream>>>(h2, tgt, out);
}

// Round 2
// 119.228 us; speedup vs baseline: 1.0926x; 1.0926x over previous
//
#include <hip/hip_runtime.h>
#include <hip/hip_bf16.h>

#define ROWS 1025   // B*N + 1
#define DD   128    // D
#define C3   384    // 3*D
#define BB   8
#define NN   128

__device__ __forceinline__ float fsigmoid(float x) {
    return __builtin_amdgcn_rcpf(1.0f + __expf(-x));
}
__device__ __forceinline__ float ftanh(float x) {
    return 1.0f - 2.0f * __builtin_amdgcn_rcpf(__expf(2.0f * x) + 1.0f);
}
__device__ __forceinline__ float bf2f(unsigned short u) {
    return __uint_as_float(((unsigned int)u) << 16);
}
__device__ __forceinline__ unsigned short f2bf(float f) {
    unsigned int i = __float_as_uint(f);            // finite data only
    return (unsigned short)((i + 0x7FFFu + ((i >> 16) & 1u)) >> 16);
}

// Transpose [B][N][N] index arrays to [B][j][i] for coalesced phase staging.
__global__ __launch_bounds__(256) void transpose_idx(
    const int* __restrict__ p, const int* __restrict__ c,
    int* __restrict__ pT, int* __restrict__ cT) {
    const int blk = blockIdx.x;           // b*16 + ti*4 + tj
    const int b = blk >> 4, ti = (blk >> 2) & 3, tj = blk & 3;
    __shared__ int tp[32][33], tc[32][33];
    const int tx = threadIdx.x & 31, ty = threadIdx.x >> 5;   // 8 rows/pass
    const size_t base = (size_t)b * NN * NN;
#pragma unroll
    for (int r = 0; r < 32; r += 8) {
        const int i = ti * 32 + ty + r, j = tj * 32 + tx;
        tp[ty + r][tx] = p[base + i * NN + j];
        tc[ty + r][tx] = c[base + i * NN + j];
    }
    __syncthreads();
#pragma unroll
    for (int r = 0; r < 32; r += 8) {
        const int j = tj * 32 + ty + r, i = ti * 32 + tx;
        pT[base + j * NN + i] = tp[tx][ty + r];
        cT[base + j * NN + i] = tc[tx][ty + r];
    }
}

// Packed gate tables:
//   GiP[row][d] = {ir, iz, in, 0} (bf16x4),  GhP[row][d] = {hr, hz, hn, h} (bf16x4)
// 4 hidden rows per block, 256 threads; thread t covers combined cols t, t+256, t+512 of 768.
__global__ __launch_bounds__(256) void gtab_kernel(
    const float* __restrict__ h,
    const float* __restrict__ Wi, const float* __restrict__ Wh,
    const float* __restrict__ bi, const float* __restrict__ bh,
    unsigned short* __restrict__ GiP, unsigned short* __restrict__ GhP) {
    __shared__ float hs[4][DD];
    const int t  = threadIdx.x;
    const int r0 = blockIdx.x * 4;
    for (int idx = t; idx < 4 * DD; idx += 256) {
        int r = idx >> 7, k = idx & (DD - 1);
        hs[r][k] = (r0 + r < ROWS) ? h[(size_t)(r0 + r) * DD + k] : 0.0f;
    }
    __syncthreads();
    if (t < DD) {
#pragma unroll
        for (int r = 0; r < 4; ++r)
            if (r0 + r < ROWS) GhP[(size_t)(r0 + r) * 512 + t * 4 + 3] = f2bf(hs[r][t]);
    }
#pragma unroll
    for (int jj = 0; jj < 3; ++jj) {
        const int  c   = t + jj * 256;     // 0..767
        const bool isI = (c < C3);
        const int  cc  = isI ? c : c - C3;
        const float* __restrict__ w = (isI ? Wi : Wh) + cc * DD;
        float acc[4] = {0.f, 0.f, 0.f, 0.f};
        for (int k = 0; k < DD; k += 4) {
            float4 wv = *reinterpret_cast<const float4*>(w + k);
#pragma unroll
            for (int r = 0; r < 4; ++r) {
                acc[r] += hs[r][k] * wv.x + hs[r][k + 1] * wv.y
                        + hs[r][k + 2] * wv.z + hs[r][k + 3] * wv.w;
            }
        }
        const float bv = (isI ? bi : bh)[cc];
        unsigned short* __restrict__ G = isI ? GiP : GhP;
        const int s = cc >> 7, d = cc & (DD - 1);
#pragma unroll
        for (int r = 0; r < 4; ++r)
            if (r0 + r < ROWS) G[(size_t)(r0 + r) * 512 + d * 4 + s] = f2bf(acc[r] + bv);
    }
}

// One block per (b,j); 512 threads = (ic 0..3) x (d 0..127); quarter ic sums 32 i's.
template<int WRITE_OUT>
__global__ __launch_bounds__(512) void phase_kernel(
    const float* __restrict__ hin,
    const int* __restrict__ xT, const int* __restrict__ hT,
    const unsigned short* __restrict__ GiP, const unsigned short* __restrict__ GhP,
    float* __restrict__ hout,
    const int* __restrict__ tgt, float* __restrict__ out) {
    const int bj = blockIdx.x;          // 0..1023
    const int t  = threadIdx.x;
    const int ic = t >> 7, d = t & (DD - 1);

    __shared__ int   xs[NN], hsx[NN];
    __shared__ float sacc[4][NN];
    if (t < NN)            xs[t]        = xT[(size_t)bj * NN + t];
    else if (t < 2 * NN)   hsx[t - NN]  = hT[(size_t)bj * NN + (t - NN)];
    __syncthreads();

    float acc = 0.0f;
#pragma unroll 4
    for (int k = 0; k < 32; ++k) {
        const int i  = ic * 32 + k;
        const int xi = xs[i];
        const int hi = hsx[i];
        const ushort4 vx = *reinterpret_cast<const ushort4*>(GiP + (size_t)xi * 512 + d * 4);
        const ushort4 vh = *reinterpret_cast<const ushort4*>(GhP + (size_t)hi * 512 + d * 4);
        const float ir = bf2f(vx.x), iz = bf2f(vx.y), in_ = bf2f(vx.z);
        const float hr = bf2f(vh.x), hz = bf2f(vh.y), hn = bf2f(vh.z), hv = bf2f(vh.w);
        const float r = fsigmoid(ir + hr);
        const float z = fsigmoid(iz + hz);
        const float n = ftanh(in_ + r * hn);
        acc += (1.0f - z) * n + z * hv;
    }
    sacc[ic][d] = acc;
    __syncthreads();

    if (ic == 0) {
        const float v   = sacc[0][d] + sacc[1][d] + sacc[2][d] + sacc[3][d];
        const int   row = 1 + bj;
        const float res = hin[(size_t)row * DD + d] + v;
        if (WRITE_OUT) {
#pragma unroll
            for (int bb = 0; bb < BB; ++bb)
                if (tgt[bb] == row) out[bb * DD + d] = res;
        } else {
            hout[(size_t)row * DD + d] = res;
        }
    } else if (ic == 1 && bj == 0) {
        if (!WRITE_OUT) hout[d] = hin[d];   // row 0 unchanged; tgt >= 1 always
    }
}

extern "C" void kernel_launch(void* const* d_in, const int* in_sizes, int n_in,
                              void* d_out, int out_size, void* d_ws, size_t ws_size,
                              hipStream_t stream) {
    const float* hidden = (const float*)d_in[0];
    const int*   parent = (const int*)d_in[1];
    const int*   child  = (const int*)d_in[2];
    const int*   tgt    = (const int*)d_in[3];
    const float* Wif    = (const float*)d_in[4];
    const float* Whf    = (const float*)d_in[5];
    const float* bif    = (const float*)d_in[6];
    const float* bhf    = (const float*)d_in[7];
    const float* Wib    = (const float*)d_in[8];
    const float* Whb    = (const float*)d_in[9];
    const float* bib    = (const float*)d_in[10];
    const float* bhb    = (const float*)d_in[11];

    char* ws = (char*)d_ws;
    unsigned short* GiP = (unsigned short*)(ws);                  // 1025*512 bf16
    unsigned short* GhP = (unsigned short*)(ws + 1049600);        // 1025*512 bf16
    float*          h1  = (float*)(ws + 2099200);                 // 1025*128 f32
    int*            pT  = (int*)(ws + 2624000);                   // 8*128*128
    int*            cT  = (int*)(ws + 3148288);                   // 8*128*128
    float* out = (float*)d_out;

    transpose_idx<<<128, 256, 0, stream>>>(parent, child, pT, cT);

    // Phase 1: bwd weights, x = child, h = parent
    gtab_kernel<<<257, 256, 0, stream>>>(hidden, Wib, Whb, bib, bhb, GiP, GhP);
    phase_kernel<0><<<BB * NN, 512, 0, stream>>>(hidden, cT, pT, GiP, GhP, h1, nullptr, nullptr);
    // Phase 2: fwd weights, x = parent, h = child; fuse tgt gather
    gtab_kernel<<<257, 256, 0, stream>>>(h1, Wif, Whf, bif, bhf, GiP, GhP);
    phase_kernel<1><<<BB * NN, 512, 0, stream>>>(h1, pT, cT, GiP, GhP, nullptr, tgt, out);
}